// Round 5
// baseline (421.870 us; speedup 1.0000x reference)
//
#include <hip/hip_runtime.h>
#include <math.h>

// PPO fused loss, round 6 (resubmit after infra failure):
//   main2: rt-outer/kk-inner loop nest (A-frags 16 VGPR live instead of 64),
//     chunk-serial GEMM1, __launch_bounds__(256,4) -> target 4 blocks/CU.
//     Per-block ADV reconstruction (block == one 64-row segment) via wave
//     shuffle suffix-scan; mean/istd precomputed by scan2.
//   aux: scan_pass3 eliminated. scan1 (in prep_all) also accumulates
//     per-segment P=Sum a, Q=Sum(b-v), R=Sum a(b-v), S2=Sum(b-v)^2, T2=Sum a^2;
//     scan2 computes SUM/SUMSQ/mean/istd in closed form (adv affine in x).
//   4 launches: prep_all -> scan2 -> main2 -> finalize.

typedef __attribute__((ext_vector_type(8))) short short8_t;
typedef __attribute__((ext_vector_type(4))) short short4_t;
typedef __attribute__((ext_vector_type(4))) float float4_t;
typedef __attribute__((ext_vector_type(2))) unsigned uint2_t;
typedef __attribute__((ext_vector_type(4))) unsigned uint4_t;

#define T_TOTAL 262144
#define S_DIM 128
#define H_DIM 1024
#define A_DIM 16
#define GAMMA 0.99f
#define LOG2E2 2.8853900817779268f   // 2*log2(e)
#define SEG_LEN 64
#define NSEG 4096
#define GRP 16
#define NGRP 256

// ws float offsets
#define WS_SUM   0
#define WS_SUMSQ 1
#define WS_MEAN  2
#define WS_ISTD  3
#define WS_TERM  4
#define WS_SEGA  8
#define WS_SEGB  (WS_SEGA + NSEG)
#define WS_INC   (WS_SEGB + NSEG)
#define WS_SEGP  (WS_INC + NSEG)
#define WS_SEGQ  (WS_SEGP + NSEG)
#define WS_SEGR  (WS_SEGQ + NSEG)
#define WS_SEGS2 (WS_SEGR + NSEG)
#define WS_SEGT2 (WS_SEGS2 + NSEG)
#define WS_B1S   (WS_SEGT2 + NSEG)          // 1024 floats (pre-scaled bias)
#define WS_W1F   (WS_B1S + 1024)            // 131072 bf16 = 65536 floats
#define WS_WHF   (WS_W1F + 65536)           // 32768 bf16 = 16384 floats

// LDS: 16 KB staging/reduce overlay + 256 B adv + 16 B term
#define SM_SIZE (16384 + 256 + 16)

__device__ __forceinline__ short f2bf(float f) {
  unsigned u = __float_as_uint(f);
  u += 0x7fffu + ((u >> 16) & 1u);
  return (short)(u >> 16);
}

// packed f32x2 -> bf16x2 (RNE), single instruction
__device__ __forceinline__ unsigned cvt_pk_bf16(float lo, float hi) {
  unsigned r;
  asm("v_cvt_pk_bf16_f32 %0, %1, %2" : "=v"(r) : "v"(lo), "v"(hi));
  return r;
}

// a lanes 32-63 <-> b lanes 0-31 (both registers updated)
__device__ __forceinline__ void permlane32_swap2(unsigned& a, unsigned& b) {
  asm("v_permlane32_swap_b32 %0, %1" : "+v"(a), "+v"(b));
}

// tanh(x + b) where bs = LOG2E2*b pre-scaled: 3 VALU + 2 trans
__device__ __forceinline__ float tanh2(float x, float bs) {
  float a = __builtin_fmaf(x, LOG2E2, bs);
  float e = __builtin_amdgcn_exp2f(a);
  float r = __builtin_amdgcn_rcpf(e + 1.0f);
  return __builtin_fmaf(r, -2.0f, 1.0f);
}

// ---------------------------------------------------------------------------
// prep_all: blocks 0-63  : W1 -> bf16 frags [nt(64)][kf(4)][lane][e(8)]
//           blocks 64-79 : W_mu|W_lv -> frags with quad-swizzled k-map
//           blocks 80-95 : scan pass 1 + stat aggregates
//           block  96    : zero accumulators + pre-scale b1
// ---------------------------------------------------------------------------
__global__ void prep_all(const float* __restrict__ W1,
                         const float* __restrict__ W_mu,
                         const float* __restrict__ W_lv,
                         const float* __restrict__ b1,
                         const float* __restrict__ rewards,
                         const int* __restrict__ masks,
                         const float* __restrict__ values,
                         float* __restrict__ ws,
                         short* __restrict__ w1f,
                         short* __restrict__ whf) {
  const int blk = blockIdx.x;
  if (blk < 64) {
    int id = blk * 256 + threadIdx.x;        // 0..16383
    int lane = id & 63;
    int kf = (id >> 6) & 3;
    int nt = id >> 8;
    int quad = lane >> 4, col = nt * 16 + (lane & 15);
    int kbase = kf * 32 + quad * 8;
#pragma unroll
    for (int e = 0; e < 8; ++e)
      w1f[(size_t)id * 8 + e] = f2bf(W1[(size_t)(kbase + e) * H_DIM + col]);
  } else if (blk < 80) {
    int id = (blk - 64) * 256 + threadIdx.x; // 0..4095
    int lane = id & 63;
    int kf = (id >> 6) & 31;
    int nt = id >> 11;
    const float* src = nt ? W_lv : W_mu;
    int quad = lane >> 4, col = lane & 15;
    // quad-swizzled k-map matching the permlane32_swap repack at runtime:
    // H(q,e) = (q>>1)*16 + (q&1)*4 + (e>>2)*8 + (e&3)
    int hbase = kf * 32 + ((quad >> 1) << 4) + ((quad & 1) << 2);
#pragma unroll
    for (int e = 0; e < 8; ++e) {
      int hh = hbase + ((e >> 2) << 3) + (e & 3);
      whf[(size_t)id * 8 + e] = f2bf(src[(size_t)hh * A_DIM + col]);
    }
  } else if (blk < 96) {
    int g = (blk - 80) * 256 + threadIdx.x;  // 0..4095 segments
    int lo = g * SEG_LEN;
    const float4* r4 = (const float4*)(rewards + lo);
    const int4* m4 = (const int4*)(masks + lo);
    const float4* v4 = (const float4*)(values + lo);
    float a = 1.0f, b = 0.0f;
    float P = 0.0f, Q = 0.0f, R = 0.0f, S2 = 0.0f, T2 = 0.0f;
#pragma unroll 4
    for (int c = 15; c >= 0; --c) {
      float4 r = r4[c]; int4 mm = m4[c]; float4 v = v4[c];
      float gi, d;
      gi = GAMMA * (float)mm.w; b = r.w + gi * b; a = gi * a;
      d = b - v.w; P += a; Q += d; R += a * d; S2 += d * d; T2 += a * a;
      gi = GAMMA * (float)mm.z; b = r.z + gi * b; a = gi * a;
      d = b - v.z; P += a; Q += d; R += a * d; S2 += d * d; T2 += a * a;
      gi = GAMMA * (float)mm.y; b = r.y + gi * b; a = gi * a;
      d = b - v.y; P += a; Q += d; R += a * d; S2 += d * d; T2 += a * a;
      gi = GAMMA * (float)mm.x; b = r.x + gi * b; a = gi * a;
      d = b - v.x; P += a; Q += d; R += a * d; S2 += d * d; T2 += a * a;
    }
    ws[WS_SEGA + g] = a;
    ws[WS_SEGB + g] = b;
    ws[WS_SEGP + g] = P;
    ws[WS_SEGQ + g] = Q;
    ws[WS_SEGR + g] = R;
    ws[WS_SEGS2 + g] = S2;
    ws[WS_SEGT2 + g] = T2;
  } else {
    if (threadIdx.x < 8) ws[threadIdx.x] = 0.0f;
    int base = threadIdx.x * 4;
    float4 bv = *(const float4*)(b1 + base);
    float4 o;
    o.x = LOG2E2 * bv.x; o.y = LOG2E2 * bv.y;
    o.z = LOG2E2 * bv.z; o.w = LOG2E2 * bv.w;
    *(float4*)(ws + WS_B1S + base) = o;
  }
}

// ---------------------------------------------------------------------------
// scan_pass2: 1 block. Computes WS_INC per segment AND global SUM/SUMSQ/
// mean/istd in closed form from the per-segment aggregates:
//   adv_i = (B_i - v_i) + A_i * x  =>  Sum adv = Q + P x;
//   Sum adv^2 = S2 + 2 R x + T2 x^2.
// ---------------------------------------------------------------------------
__global__ void scan_pass2(float* __restrict__ ws) {
  __shared__ float gA[NGRP], gB[NGRP], ginc[NGRP];
  __shared__ float rs1[4], rs2[4];
  int t = threadIdx.x;
  int lo = t * GRP, hi = lo + GRP - 1;
  float A = 1.0f, B = 0.0f;
  for (int s = hi; s >= lo; --s) {
    float as = ws[WS_SEGA + s], bs = ws[WS_SEGB + s];
    B = bs + as * B;
    A = as * A;
  }
  gA[t] = A; gB[t] = B;
  __syncthreads();
  if (t == 0) {
    float x = 0.0f;
    ginc[NGRP - 1] = 0.0f;
    for (int g = NGRP - 1; g >= 1; --g) {
      x = gB[g] + gA[g] * x;
      ginc[g - 1] = x;
    }
  }
  __syncthreads();
  float x = ginc[t];
  float sum = 0.0f, sumsq = 0.0f;
  for (int s = hi; s >= lo; --s) {
    ws[WS_INC + s] = x;
    float P = ws[WS_SEGP + s], Q = ws[WS_SEGQ + s], R = ws[WS_SEGR + s];
    float S2 = ws[WS_SEGS2 + s], T2 = ws[WS_SEGT2 + s];
    sum += Q + P * x;
    sumsq += S2 + (2.0f * R + T2 * x) * x;
    x = ws[WS_SEGB + s] + ws[WS_SEGA + s] * x;
  }
  int lane = t & 63, wv = t >> 6;
#pragma unroll
  for (int m = 1; m < 64; m <<= 1) {
    sum += __shfl_xor(sum, m);
    sumsq += __shfl_xor(sumsq, m);
  }
  if (lane == 0) { rs1[wv] = sum; rs2[wv] = sumsq; }
  __syncthreads();
  if (t == 0) {
    float s1 = rs1[0] + rs1[1] + rs1[2] + rs1[3];
    float s2 = rs2[0] + rs2[1] + rs2[2] + rs2[3];
    float n = (float)T_TOTAL;
    ws[WS_SUM] = s1;
    ws[WS_SUMSQ] = s2;
    float mean = s1 / n;
    float var = (s2 - s1 * s1 / n) / (n - 1.0f);
    var = fmaxf(var, 0.0f);
    ws[WS_MEAN] = mean;
    ws[WS_ISTD] = 1.0f / (sqrtf(var) + 1e-7f);
  }
}

// ---------------------------------------------------------------------------
// main2: 64 rows/block, 256 threads (4 waves), 4 blocks/CU target.
// rt-outer / kk-inner: only the current row-tile's A-frags (16 VGPR) live.
// ---------------------------------------------------------------------------
__launch_bounds__(256, 4)
__global__ void main2(const float* __restrict__ states,
                      const float* __restrict__ actions,
                      const float* __restrict__ beta,
                      const float* __restrict__ rewards,
                      const int* __restrict__ masks,
                      const float* __restrict__ values,
                      const float* __restrict__ b1s,
                      const float* __restrict__ bmug,
                      const float* __restrict__ blvg,
                      const short* __restrict__ W1f,
                      const short* __restrict__ Whf,
                      float* __restrict__ ws) {
  __shared__ __align__(16) unsigned char smem[SM_SIZE];
  short* Ab = (short*)smem;
  float* adv_lds = (float*)(smem + 16384);
  float* lds_term = (float*)(smem + 16384 + 256);

  const int tid = threadIdx.x;
  const int lane = tid & 63;
  const int w = tid >> 6;
  const int quad = lane >> 4;
  const int t0 = blockIdx.x * 64;

  // ---- wave 0: reconstruct this block's 64 advantages (block==segment) ----
  if (w == 0) {
    float r = rewards[t0 + lane];
    float g = GAMMA * (float)masks[t0 + lane];
    float v = values[t0 + lane];
    float SA = g, SB = r;
#pragma unroll
    for (int off = 1; off < 64; off <<= 1) {
      float tA = __shfl_down(SA, off);
      float tB = __shfl_down(SB, off);
      if (lane + off < 64) { SB = SB + SA * tB; SA = SA * tA; }
    }
    float x = ws[WS_INC + blockIdx.x];
    adv_lds[lane] = (SB + SA * x) - v;
  }

  // ---- stage states (64x128 fp32) -> bf16 fragments in LDS ----
  {
    const float4* src = (const float4*)(states + (size_t)t0 * S_DIM);
#pragma unroll
    for (int i = 0; i < 8; ++i) {
      int f = tid + i * 256;
      float4 v = src[f];
      int row = f >> 5, kq = f & 31;
      int rt = row >> 4, rr = row & 15;
      int k = kq * 4, kf = k >> 5, qd = (k >> 3) & 3, j0 = k & 7;
      uint2_t pk2;
      pk2[0] = cvt_pk_bf16(v.x, v.y);
      pk2[1] = cvt_pk_bf16(v.z, v.w);
      *(uint2_t*)(Ab + (((rt * 4 + kf) * 64 + qd * 16 + rr) << 3) + j0) = pk2;
    }
  }
  __syncthreads();

  float4_t acc2[4][2];
#pragma unroll
  for (int rt = 0; rt < 4; ++rt) {
    acc2[rt][0] = (float4_t){0.f, 0.f, 0.f, 0.f};
    acc2[rt][1] = (float4_t){0.f, 0.f, 0.f, 0.f};
  }
  const float4_t zz = (float4_t){0.f, 0.f, 0.f, 0.f};

  for (int rt = 0; rt < 4; ++rt) {
    // this row-tile's A-fragments (16 VGPR live)
    short8_t sf[4];
#pragma unroll
    for (int kf = 0; kf < 4; ++kf)
      sf[kf] = *((const short8_t*)Ab + (rt * 4 + kf) * 64 + lane);

    for (int kk = 0; kk < 8; ++kk) {
      const int kf2 = w * 8 + kk;               // GEMM2 K-chunk
      const short8_t* whp = (const short8_t*)Whf + kf2 * 64 + lane;
      const short8_t wmu = whp[0];
      const short8_t wlv = whp[2048];           // nt=1 block (32*64 frags)
      const int nt0 = w * 16 + kk * 2;          // wave's H-tile pair
      const short8_t* w1p = (const short8_t*)W1f + nt0 * 256 + lane;

      // chunk 0: 16 H-cols
      float4_t c0 = zz;
      c0 = __builtin_amdgcn_mfma_f32_16x16x32_bf16(w1p[0],   sf[0], c0, 0, 0, 0);
      c0 = __builtin_amdgcn_mfma_f32_16x16x32_bf16(w1p[64],  sf[1], c0, 0, 0, 0);
      c0 = __builtin_amdgcn_mfma_f32_16x16x32_bf16(w1p[128], sf[2], c0, 0, 0, 0);
      c0 = __builtin_amdgcn_mfma_f32_16x16x32_bf16(w1p[192], sf[3], c0, 0, 0, 0);
      const float4 b1a = *(const float4*)(b1s + nt0 * 16 + quad * 4);
      unsigned p00 = cvt_pk_bf16(tanh2(c0[0], b1a.x), tanh2(c0[1], b1a.y));
      unsigned p01 = cvt_pk_bf16(tanh2(c0[2], b1a.z), tanh2(c0[3], b1a.w));

      // chunk 1: next 16 H-cols
      float4_t c1 = zz;
      c1 = __builtin_amdgcn_mfma_f32_16x16x32_bf16(w1p[256], sf[0], c1, 0, 0, 0);
      c1 = __builtin_amdgcn_mfma_f32_16x16x32_bf16(w1p[320], sf[1], c1, 0, 0, 0);
      c1 = __builtin_amdgcn_mfma_f32_16x16x32_bf16(w1p[384], sf[2], c1, 0, 0, 0);
      c1 = __builtin_amdgcn_mfma_f32_16x16x32_bf16(w1p[448], sf[3], c1, 0, 0, 0);
      const float4 b1b = *(const float4*)(b1s + nt0 * 16 + 16 + quad * 4);
      unsigned p10 = cvt_pk_bf16(tanh2(c1[0], b1b.x), tanh2(c1[1], b1b.y));
      unsigned p11 = cvt_pk_bf16(tanh2(c1[2], b1b.z), tanh2(c1[3], b1b.w));

      // cross-quad repack -> GEMM2 B-fragment; accumulate heads
      permlane32_swap2(p00, p10);   // p00 = low halves, p10 = high halves
      permlane32_swap2(p01, p11);
      uint4_t u = (uint4_t){p00, p01, p10, p11};
      short8_t b2 = __builtin_bit_cast(short8_t, u);
      acc2[rt][0] = __builtin_amdgcn_mfma_f32_16x16x32_bf16(wmu, b2, acc2[rt][0], 0, 0, 0);
      acc2[rt][1] = __builtin_amdgcn_mfma_f32_16x16x32_bf16(wlv, b2, acc2[rt][1], 0, 0, 0);
    }
  }

  // ---- two-round cross-wave reduce in 16 KB (overlays staging) ----
  __syncthreads();
  float* red = (float*)smem;
  if (w < 2) {
#pragma unroll
    for (int rt = 0; rt < 4; ++rt)
#pragma unroll
      for (int nt = 0; nt < 2; ++nt)
        *(float4_t*)(red + ((((w & 1) * 8 + rt * 2 + nt) * 64 + lane) << 2)) = acc2[rt][nt];
  }
  __syncthreads();
  if (w >= 2) {
#pragma unroll
    for (int rt = 0; rt < 4; ++rt)
#pragma unroll
      for (int nt = 0; nt < 2; ++nt) {
        float* p = red + ((((w & 1) * 8 + rt * 2 + nt) * 64 + lane) << 2);
        float4_t v = *(float4_t*)p;
        v += acc2[rt][nt];
        *(float4_t*)p = v;
      }
  }
  __syncthreads();

  const float mean = ws[WS_MEAN], istd = ws[WS_ISTD];

  // epilogue: wave w handles row-tile rt = w; C2 col = t at lane&15,
  // row = a at quad*4+reg
  const int rt = w;
  const int tcol = lane & 15;
  const int t = t0 + rt * 16 + tcol;
  const float4 bmu4 = *(const float4*)(bmug + quad * 4);
  const float4 blv4 = *(const float4*)(blvg + quad * 4);
  float m0 = bmu4.x, m1 = bmu4.y, m2 = bmu4.z, m3 = bmu4.w;
  float l0 = blv4.x, l1 = blv4.y, l2 = blv4.z, l3 = blv4.w;
  const float4_t* rp = (const float4_t*)red;
#pragma unroll
  for (int r = 0; r < 2; ++r) {
    float4_t mv = rp[(r * 8 + rt * 2 + 0) * 64 + lane];
    float4_t lvv = rp[(r * 8 + rt * 2 + 1) * 64 + lane];
    m0 += mv[0]; m1 += mv[1]; m2 += mv[2]; m3 += mv[3];
    l0 += lvv[0]; l1 += lvv[1]; l2 += lvv[2]; l3 += lvv[3];
  }
  const float4 av = *(const float4*)(actions + (size_t)t * A_DIM + quad * 4);
  const float4 bv = *(const float4*)(beta + (size_t)t * A_DIM + quad * 4);
  float d = 0.0f;
  {
    float isd, z;
    isd = __expf(-0.5f * l0); z = (av.x - m0) * isd;
    d += -0.5f * z * z - 0.5f * l0 - 0.9189385332046727f - bv.x;
    isd = __expf(-0.5f * l1); z = (av.y - m1) * isd;
    d += -0.5f * z * z - 0.5f * l1 - 0.9189385332046727f - bv.y;
    isd = __expf(-0.5f * l2); z = (av.z - m2) * isd;
    d += -0.5f * z * z - 0.5f * l2 - 0.9189385332046727f - bv.z;
    isd = __expf(-0.5f * l3); z = (av.w - m3) * isd;
    d += -0.5f * z * z - 0.5f * l3 - 0.9189385332046727f - bv.w;
  }
  d += __shfl_xor(d, 16);
  d += __shfl_xor(d, 32);
  float term = 0.0f;
  if (quad == 0) {
    float ratio = __expf(d);
    float ah = (adv_lds[rt * 16 + tcol] - mean) * istd;
    float rc = fminf(fmaxf(ratio, 0.8f), 1.2f);
    term = fminf(ratio * ah, rc * ah);
  }
  term += __shfl_xor(term, 1);
  term += __shfl_xor(term, 2);
  term += __shfl_xor(term, 4);
  term += __shfl_xor(term, 8);
  if (lane == 0) lds_term[w] = term;
  __syncthreads();
  if (tid == 0)
    atomicAdd(&ws[WS_TERM], lds_term[0] + lds_term[1] + lds_term[2] + lds_term[3]);
}

__global__ void finalize(const float* __restrict__ ws, float* __restrict__ out) {
  if (threadIdx.x == 0) {
    float n = (float)T_TOTAL;
    out[0] = ws[WS_SUMSQ] / n - ws[WS_TERM] / n;
  }
}

extern "C" void kernel_launch(void* const* d_in, const int* in_sizes, int n_in,
                              void* d_out, int out_size, void* d_ws, size_t ws_size,
                              hipStream_t stream) {
  const float* states  = (const float*)d_in[0];
  const float* actions = (const float*)d_in[1];
  const float* rewards = (const float*)d_in[2];
  const float* values  = (const float*)d_in[3];
  const float* beta    = (const float*)d_in[4];
  const float* W1      = (const float*)d_in[5];
  const float* b1      = (const float*)d_in[6];
  const float* W_mu    = (const float*)d_in[7];
  const float* b_mu    = (const float*)d_in[8];
  const float* W_lv    = (const float*)d_in[9];
  const float* b_lv    = (const float*)d_in[10];
  const int*   masks   = (const int*)d_in[11];
  float* ws = (float*)d_ws;
  float* out = (float*)d_out;
  short* w1f = (short*)(ws + WS_W1F);
  short* whf = (short*)(ws + WS_WHF);
  const float* b1s = ws + WS_B1S;

  hipLaunchKernelGGL(prep_all, dim3(97), dim3(256), 0, stream,
                     W1, W_mu, W_lv, b1, rewards, masks, values, ws, w1f, whf);
  hipLaunchKernelGGL(scan_pass2, dim3(1), dim3(NGRP), 0, stream, ws);
  hipLaunchKernelGGL(main2, dim3(T_TOTAL / 64), dim3(256), 0, stream,
                     states, actions, beta, rewards, masks, values,
                     b1s, b_mu, b_lv, w1f, whf, ws);
  hipLaunchKernelGGL(finalize, dim3(1), dim3(64), 0, stream, ws, out);
}

// Round 6
// 327.207 us; speedup vs baseline: 1.2893x; 1.2893x over previous
//
#include <hip/hip_runtime.h>
#include <math.h>

// PPO fused loss, round 7 = round-3 main2 (best measured: 144.5us) + round-5
// aux (scan_pass3 eliminated; in-block adv reconstruction; closed-form stats).
//   main2: kk-outer / rt-inner, sfrag[4][4] register-resident (operand reuse
//     + 4-way cross-rt ILP — round-5's rt-outer refetch variant regressed),
//     launch_bounds(256,2), lean tanh (fma+exp2+add+rcp+fma), 16.9 KB LDS.
//   4 launches: prep_all -> scan_pass2 -> main2 -> finalize.

typedef __attribute__((ext_vector_type(8))) short short8_t;
typedef __attribute__((ext_vector_type(4))) short short4_t;
typedef __attribute__((ext_vector_type(4))) float float4_t;
typedef __attribute__((ext_vector_type(2))) unsigned uint2_t;
typedef __attribute__((ext_vector_type(4))) unsigned uint4_t;

#define T_TOTAL 262144
#define S_DIM 128
#define H_DIM 1024
#define A_DIM 16
#define GAMMA 0.99f
#define LOG2E2 2.8853900817779268f   // 2*log2(e)
#define SEG_LEN 64
#define NSEG 4096
#define GRP 16
#define NGRP 256

// ws float offsets
#define WS_SUM   0
#define WS_SUMSQ 1
#define WS_MEAN  2
#define WS_ISTD  3
#define WS_TERM  4
#define WS_SEGA  8
#define WS_SEGB  (WS_SEGA + NSEG)
#define WS_INC   (WS_SEGB + NSEG)
#define WS_SEGP  (WS_INC + NSEG)
#define WS_SEGQ  (WS_SEGP + NSEG)
#define WS_SEGR  (WS_SEGQ + NSEG)
#define WS_SEGS2 (WS_SEGR + NSEG)
#define WS_SEGT2 (WS_SEGS2 + NSEG)
#define WS_B1S   (WS_SEGT2 + NSEG)          // 1024 floats (pre-scaled bias)
#define WS_W1F   (WS_B1S + 1024)            // 131072 bf16 = 65536 floats
#define WS_WHF   (WS_W1F + 65536)           // 32768 bf16 = 16384 floats

// LDS: 16 KB staging/reduce overlay + 256 B adv + 16 B term
#define SM_SIZE (16384 + 256 + 16)

__device__ __forceinline__ short f2bf(float f) {
  unsigned u = __float_as_uint(f);
  u += 0x7fffu + ((u >> 16) & 1u);
  return (short)(u >> 16);
}

// packed f32x2 -> bf16x2 (RNE), single instruction
__device__ __forceinline__ unsigned cvt_pk_bf16(float lo, float hi) {
  unsigned r;
  asm("v_cvt_pk_bf16_f32 %0, %1, %2" : "=v"(r) : "v"(lo), "v"(hi));
  return r;
}

// a lanes 32-63 <-> b lanes 0-31 (both registers updated)
__device__ __forceinline__ void permlane32_swap2(unsigned& a, unsigned& b) {
  asm("v_permlane32_swap_b32 %0, %1" : "+v"(a), "+v"(b));
}

// tanh(x + b) where bs = LOG2E2*b pre-scaled: 3 VALU + 2 trans
__device__ __forceinline__ float tanh2(float x, float bs) {
  float a = __builtin_fmaf(x, LOG2E2, bs);
  float e = __builtin_amdgcn_exp2f(a);
  float r = __builtin_amdgcn_rcpf(e + 1.0f);
  return __builtin_fmaf(r, -2.0f, 1.0f);
}

// ---------------------------------------------------------------------------
// prep_all: blocks 0-63  : W1 -> bf16 frags [nt(64)][kf(4)][lane][e(8)]
//           blocks 64-79 : W_mu|W_lv -> frags with quad-swizzled k-map
//           blocks 80-95 : scan pass 1 + stat aggregates
//           block  96    : zero accumulators + pre-scale b1
// ---------------------------------------------------------------------------
__global__ void prep_all(const float* __restrict__ W1,
                         const float* __restrict__ W_mu,
                         const float* __restrict__ W_lv,
                         const float* __restrict__ b1,
                         const float* __restrict__ rewards,
                         const int* __restrict__ masks,
                         const float* __restrict__ values,
                         float* __restrict__ ws,
                         short* __restrict__ w1f,
                         short* __restrict__ whf) {
  const int blk = blockIdx.x;
  if (blk < 64) {
    int id = blk * 256 + threadIdx.x;        // 0..16383
    int lane = id & 63;
    int kf = (id >> 6) & 3;
    int nt = id >> 8;
    int quad = lane >> 4, col = nt * 16 + (lane & 15);
    int kbase = kf * 32 + quad * 8;
#pragma unroll
    for (int e = 0; e < 8; ++e)
      w1f[(size_t)id * 8 + e] = f2bf(W1[(size_t)(kbase + e) * H_DIM + col]);
  } else if (blk < 80) {
    int id = (blk - 64) * 256 + threadIdx.x; // 0..4095
    int lane = id & 63;
    int kf = (id >> 6) & 31;
    int nt = id >> 11;
    const float* src = nt ? W_lv : W_mu;
    int quad = lane >> 4, col = lane & 15;
    // quad-swizzled k-map matching the permlane32_swap repack at runtime:
    // H(q,e) = (q>>1)*16 + (q&1)*4 + (e>>2)*8 + (e&3)
    int hbase = kf * 32 + ((quad >> 1) << 4) + ((quad & 1) << 2);
#pragma unroll
    for (int e = 0; e < 8; ++e) {
      int hh = hbase + ((e >> 2) << 3) + (e & 3);
      whf[(size_t)id * 8 + e] = f2bf(src[(size_t)hh * A_DIM + col]);
    }
  } else if (blk < 96) {
    int g = (blk - 80) * 256 + threadIdx.x;  // 0..4095 segments
    int lo = g * SEG_LEN;
    const float4* r4 = (const float4*)(rewards + lo);
    const int4* m4 = (const int4*)(masks + lo);
    const float4* v4 = (const float4*)(values + lo);
    float a = 1.0f, b = 0.0f;
    float P = 0.0f, Q = 0.0f, R = 0.0f, S2 = 0.0f, T2 = 0.0f;
#pragma unroll 4
    for (int c = 15; c >= 0; --c) {
      float4 r = r4[c]; int4 mm = m4[c]; float4 v = v4[c];
      float gi, d;
      gi = GAMMA * (float)mm.w; b = r.w + gi * b; a = gi * a;
      d = b - v.w; P += a; Q += d; R += a * d; S2 += d * d; T2 += a * a;
      gi = GAMMA * (float)mm.z; b = r.z + gi * b; a = gi * a;
      d = b - v.z; P += a; Q += d; R += a * d; S2 += d * d; T2 += a * a;
      gi = GAMMA * (float)mm.y; b = r.y + gi * b; a = gi * a;
      d = b - v.y; P += a; Q += d; R += a * d; S2 += d * d; T2 += a * a;
      gi = GAMMA * (float)mm.x; b = r.x + gi * b; a = gi * a;
      d = b - v.x; P += a; Q += d; R += a * d; S2 += d * d; T2 += a * a;
    }
    ws[WS_SEGA + g] = a;
    ws[WS_SEGB + g] = b;
    ws[WS_SEGP + g] = P;
    ws[WS_SEGQ + g] = Q;
    ws[WS_SEGR + g] = R;
    ws[WS_SEGS2 + g] = S2;
    ws[WS_SEGT2 + g] = T2;
  } else {
    if (threadIdx.x < 8) ws[threadIdx.x] = 0.0f;
    int base = threadIdx.x * 4;
    float4 bv = *(const float4*)(b1 + base);
    float4 o;
    o.x = LOG2E2 * bv.x; o.y = LOG2E2 * bv.y;
    o.z = LOG2E2 * bv.z; o.w = LOG2E2 * bv.w;
    *(float4*)(ws + WS_B1S + base) = o;
  }
}

// ---------------------------------------------------------------------------
// scan_pass2: 1 block. Computes WS_INC per segment AND global SUM/SUMSQ/
// mean/istd in closed form from the per-segment aggregates:
//   adv_i = (B_i - v_i) + A_i * x  =>  Sum adv = Q + P x;
//   Sum adv^2 = S2 + 2 R x + T2 x^2.
// ---------------------------------------------------------------------------
__global__ void scan_pass2(float* __restrict__ ws) {
  __shared__ float gA[NGRP], gB[NGRP], ginc[NGRP];
  __shared__ float rs1[4], rs2[4];
  int t = threadIdx.x;
  int lo = t * GRP, hi = lo + GRP - 1;
  float A = 1.0f, B = 0.0f;
  for (int s = hi; s >= lo; --s) {
    float as = ws[WS_SEGA + s], bs = ws[WS_SEGB + s];
    B = bs + as * B;
    A = as * A;
  }
  gA[t] = A; gB[t] = B;
  __syncthreads();
  if (t == 0) {
    float x = 0.0f;
    ginc[NGRP - 1] = 0.0f;
    for (int g = NGRP - 1; g >= 1; --g) {
      x = gB[g] + gA[g] * x;
      ginc[g - 1] = x;
    }
  }
  __syncthreads();
  float x = ginc[t];
  float sum = 0.0f, sumsq = 0.0f;
  for (int s = hi; s >= lo; --s) {
    ws[WS_INC + s] = x;
    float P = ws[WS_SEGP + s], Q = ws[WS_SEGQ + s], R = ws[WS_SEGR + s];
    float S2 = ws[WS_SEGS2 + s], T2 = ws[WS_SEGT2 + s];
    sum += Q + P * x;
    sumsq += S2 + (2.0f * R + T2 * x) * x;
    x = ws[WS_SEGB + s] + ws[WS_SEGA + s] * x;
  }
  int lane = t & 63, wv = t >> 6;
#pragma unroll
  for (int m = 1; m < 64; m <<= 1) {
    sum += __shfl_xor(sum, m);
    sumsq += __shfl_xor(sumsq, m);
  }
  if (lane == 0) { rs1[wv] = sum; rs2[wv] = sumsq; }
  __syncthreads();
  if (t == 0) {
    float s1 = rs1[0] + rs1[1] + rs1[2] + rs1[3];
    float s2 = rs2[0] + rs2[1] + rs2[2] + rs2[3];
    float n = (float)T_TOTAL;
    ws[WS_SUM] = s1;
    ws[WS_SUMSQ] = s2;
    float mean = s1 / n;
    float var = (s2 - s1 * s1 / n) / (n - 1.0f);
    var = fmaxf(var, 0.0f);
    ws[WS_MEAN] = mean;
    ws[WS_ISTD] = 1.0f / (sqrtf(var) + 1e-7f);
  }
}

// ---------------------------------------------------------------------------
// main2: 64 rows/block, 256 threads (4 waves). Wave w owns H in
// [w*256,(w+1)*256) (GEMM2 K-split). kk-outer / rt-inner: sfrag[4][4]
// register-resident (W1f/Whf read once per kk), 4-way cross-rt ILP.
// ---------------------------------------------------------------------------
__launch_bounds__(256, 2)
__global__ void main2(const float* __restrict__ states,
                      const float* __restrict__ actions,
                      const float* __restrict__ beta,
                      const float* __restrict__ rewards,
                      const int* __restrict__ masks,
                      const float* __restrict__ values,
                      const float* __restrict__ b1s,
                      const float* __restrict__ bmug,
                      const float* __restrict__ blvg,
                      const short* __restrict__ W1f,
                      const short* __restrict__ Whf,
                      float* __restrict__ ws) {
  __shared__ __align__(16) unsigned char smem[SM_SIZE];
  short* Ab = (short*)smem;
  float* adv_lds = (float*)(smem + 16384);
  float* lds_term = (float*)(smem + 16384 + 256);

  const int tid = threadIdx.x;
  const int lane = tid & 63;
  const int w = tid >> 6;
  const int quad = lane >> 4;
  const int t0 = blockIdx.x * 64;

  // ---- wave 0: reconstruct this block's 64 advantages (block==segment) ----
  if (w == 0) {
    float r = rewards[t0 + lane];
    float g = GAMMA * (float)masks[t0 + lane];
    float v = values[t0 + lane];
    float SA = g, SB = r;
#pragma unroll
    for (int off = 1; off < 64; off <<= 1) {
      float tA = __shfl_down(SA, off);
      float tB = __shfl_down(SB, off);
      if (lane + off < 64) { SB = SB + SA * tB; SA = SA * tA; }
    }
    float x = ws[WS_INC + blockIdx.x];
    adv_lds[lane] = (SB + SA * x) - v;
  }

  // ---- stage states (64x128 fp32) -> bf16 fragments in LDS ----
  {
    const float4* src = (const float4*)(states + (size_t)t0 * S_DIM);
#pragma unroll
    for (int i = 0; i < 8; ++i) {
      int f = tid + i * 256;
      float4 v = src[f];
      int row = f >> 5, kq = f & 31;
      int rt = row >> 4, rr = row & 15;
      int k = kq * 4, kf = k >> 5, qd = (k >> 3) & 3, j0 = k & 7;
      uint2_t pk2;
      pk2[0] = cvt_pk_bf16(v.x, v.y);
      pk2[1] = cvt_pk_bf16(v.z, v.w);
      *(uint2_t*)(Ab + (((rt * 4 + kf) * 64 + qd * 16 + rr) << 3) + j0) = pk2;
    }
  }
  __syncthreads();

  // states fragments -> registers (t at lane&15, k at quad*8+e)
  short8_t sfrag[4][4];
#pragma unroll
  for (int rt = 0; rt < 4; ++rt)
#pragma unroll
    for (int kf = 0; kf < 4; ++kf)
      sfrag[rt][kf] = *((const short8_t*)Ab + (rt * 4 + kf) * 64 + lane);

  float4_t acc2[4][2];
#pragma unroll
  for (int rt = 0; rt < 4; ++rt) {
    acc2[rt][0] = (float4_t){0.f, 0.f, 0.f, 0.f};
    acc2[rt][1] = (float4_t){0.f, 0.f, 0.f, 0.f};
  }
  const float4_t zz = (float4_t){0.f, 0.f, 0.f, 0.f};

  for (int kk = 0; kk < 8; ++kk) {
    const int nt1 = w * 16 + kk * 2;          // wave's H-tile pair
    const short8_t* w1p = (const short8_t*)W1f + nt1 * 256 + lane;
    short8_t wf0[4], wf1[4];
#pragma unroll
    for (int kf = 0; kf < 4; ++kf) {
      wf0[kf] = w1p[kf * 64];
      wf1[kf] = w1p[256 + kf * 64];
    }
    const float4 b1a = *(const float4*)(b1s + nt1 * 16 + quad * 4);
    const float4 b1b = *(const float4*)(b1s + nt1 * 16 + 16 + quad * 4);
    const int kf2 = w * 8 + kk;               // GEMM2 K-chunk
    const short8_t* whp = (const short8_t*)Whf + kf2 * 64 + lane;
    const short8_t wmu = whp[0];
    const short8_t wlv = whp[2048];           // nt=1 block (32*64 frags)
#pragma unroll
    for (int rt = 0; rt < 4; ++rt) {
      // GEMM1 (swapped): C1 = h^T tiles; bias applied inside tanh2
      float4_t c0 = zz;
      float4_t c1 = zz;
#pragma unroll
      for (int kf = 0; kf < 4; ++kf) {
        c0 = __builtin_amdgcn_mfma_f32_16x16x32_bf16(wf0[kf], sfrag[rt][kf], c0, 0, 0, 0);
        c1 = __builtin_amdgcn_mfma_f32_16x16x32_bf16(wf1[kf], sfrag[rt][kf], c1, 0, 0, 0);
      }
      // tanh + pack + cross-quad repack into GEMM2 B-fragment
      unsigned p00 = cvt_pk_bf16(tanh2(c0[0], b1a.x), tanh2(c0[1], b1a.y));
      unsigned p01 = cvt_pk_bf16(tanh2(c0[2], b1a.z), tanh2(c0[3], b1a.w));
      unsigned p10 = cvt_pk_bf16(tanh2(c1[0], b1b.x), tanh2(c1[1], b1b.y));
      unsigned p11 = cvt_pk_bf16(tanh2(c1[2], b1b.z), tanh2(c1[3], b1b.w));
      permlane32_swap2(p00, p10);   // p00 = low halves, p10 = high halves
      permlane32_swap2(p01, p11);
      uint4_t u = (uint4_t){p00, p01, p10, p11};
      short8_t b2 = __builtin_bit_cast(short8_t, u);
      acc2[rt][0] = __builtin_amdgcn_mfma_f32_16x16x32_bf16(wmu, b2, acc2[rt][0], 0, 0, 0);
      acc2[rt][1] = __builtin_amdgcn_mfma_f32_16x16x32_bf16(wlv, b2, acc2[rt][1], 0, 0, 0);
    }
  }

  // ---- two-round cross-wave reduce in 16 KB (overlays staging) ----
  __syncthreads();
  float* red = (float*)smem;
  if (w < 2) {
#pragma unroll
    for (int rt = 0; rt < 4; ++rt)
#pragma unroll
      for (int nt = 0; nt < 2; ++nt)
        *(float4_t*)(red + ((((w & 1) * 8 + rt * 2 + nt) * 64 + lane) << 2)) = acc2[rt][nt];
  }
  __syncthreads();
  if (w >= 2) {
#pragma unroll
    for (int rt = 0; rt < 4; ++rt)
#pragma unroll
      for (int nt = 0; nt < 2; ++nt) {
        float* p = red + ((((w & 1) * 8 + rt * 2 + nt) * 64 + lane) << 2);
        float4_t v = *(float4_t*)p;
        v += acc2[rt][nt];
        *(float4_t*)p = v;
      }
  }
  __syncthreads();

  const float mean = ws[WS_MEAN], istd = ws[WS_ISTD];

  // epilogue: wave w handles row-tile rt = w; C2 col = t at lane&15,
  // row = a at quad*4+reg
  const int rt = w;
  const int tcol = lane & 15;
  const int t = t0 + rt * 16 + tcol;
  const float4 bmu4 = *(const float4*)(bmug + quad * 4);
  const float4 blv4 = *(const float4*)(blvg + quad * 4);
  float m0 = bmu4.x, m1 = bmu4.y, m2 = bmu4.z, m3 = bmu4.w;
  float l0 = blv4.x, l1 = blv4.y, l2 = blv4.z, l3 = blv4.w;
  const float4_t* rp = (const float4_t*)red;
#pragma unroll
  for (int r = 0; r < 2; ++r) {
    float4_t mv = rp[(r * 8 + rt * 2 + 0) * 64 + lane];
    float4_t lvv = rp[(r * 8 + rt * 2 + 1) * 64 + lane];
    m0 += mv[0]; m1 += mv[1]; m2 += mv[2]; m3 += mv[3];
    l0 += lvv[0]; l1 += lvv[1]; l2 += lvv[2]; l3 += lvv[3];
  }
  const float4 av = *(const float4*)(actions + (size_t)t * A_DIM + quad * 4);
  const float4 bv = *(const float4*)(beta + (size_t)t * A_DIM + quad * 4);
  float d = 0.0f;
  {
    float isd, z;
    isd = __expf(-0.5f * l0); z = (av.x - m0) * isd;
    d += -0.5f * z * z - 0.5f * l0 - 0.9189385332046727f - bv.x;
    isd = __expf(-0.5f * l1); z = (av.y - m1) * isd;
    d += -0.5f * z * z - 0.5f * l1 - 0.9189385332046727f - bv.y;
    isd = __expf(-0.5f * l2); z = (av.z - m2) * isd;
    d += -0.5f * z * z - 0.5f * l2 - 0.9189385332046727f - bv.z;
    isd = __expf(-0.5f * l3); z = (av.w - m3) * isd;
    d += -0.5f * z * z - 0.5f * l3 - 0.9189385332046727f - bv.w;
  }
  d += __shfl_xor(d, 16);
  d += __shfl_xor(d, 32);
  float term = 0.0f;
  if (quad == 0) {
    float ratio = __expf(d);
    float ah = (adv_lds[rt * 16 + tcol] - mean) * istd;
    float rc = fminf(fmaxf(ratio, 0.8f), 1.2f);
    term = fminf(ratio * ah, rc * ah);
  }
  term += __shfl_xor(term, 1);
  term += __shfl_xor(term, 2);
  term += __shfl_xor(term, 4);
  term += __shfl_xor(term, 8);
  if (lane == 0) lds_term[w] = term;
  __syncthreads();
  if (tid == 0)
    atomicAdd(&ws[WS_TERM], lds_term[0] + lds_term[1] + lds_term[2] + lds_term[3]);
}

__global__ void finalize(const float* __restrict__ ws, float* __restrict__ out) {
  if (threadIdx.x == 0) {
    float n = (float)T_TOTAL;
    out[0] = ws[WS_SUMSQ] / n - ws[WS_TERM] / n;
  }
}

extern "C" void kernel_launch(void* const* d_in, const int* in_sizes, int n_in,
                              void* d_out, int out_size, void* d_ws, size_t ws_size,
                              hipStream_t stream) {
  const float* states  = (const float*)d_in[0];
  const float* actions = (const float*)d_in[1];
  const float* rewards = (const float*)d_in[2];
  const float* values  = (const float*)d_in[3];
  const float* beta    = (const float*)d_in[4];
  const float* W1      = (const float*)d_in[5];
  const float* b1      = (const float*)d_in[6];
  const float* W_mu    = (const float*)d_in[7];
  const float* b_mu    = (const float*)d_in[8];
  const float* W_lv    = (const float*)d_in[9];
  const float* b_lv    = (const float*)d_in[10];
  const int*   masks   = (const int*)d_in[11];
  float* ws = (float*)d_ws;
  float* out = (float*)d_out;
  short* w1f = (short*)(ws + WS_W1F);
  short* whf = (short*)(ws + WS_WHF);
  const float* b1s = ws + WS_B1S;

  hipLaunchKernelGGL(prep_all, dim3(97), dim3(256), 0, stream,
                     W1, W_mu, W_lv, b1, rewards, masks, values, ws, w1f, whf);
  hipLaunchKernelGGL(scan_pass2, dim3(1), dim3(NGRP), 0, stream, ws);
  hipLaunchKernelGGL(main2, dim3(T_TOTAL / 64), dim3(256), 0, stream,
                     states, actions, beta, rewards, masks, values,
                     b1s, b_mu, b_lv, w1f, whf, ws);
  hipLaunchKernelGGL(finalize, dim3(1), dim3(64), 0, stream, ws, out);
}